// Round 3
// baseline (484.147 us; speedup 1.0000x reference)
//
#include <hip/hip_runtime.h>
#include <stdint.h>

#define NH 16
#define HD 64
#define SQ 1024
#define SK 4096
#define DM 1024
#define MQ 2048      // B*Sq
#define MK 8192      // B*Sk
#define MTOT 18432   // MQ + MK + MK

typedef short s16x8 __attribute__((ext_vector_type(8)));
typedef float f32x4 __attribute__((ext_vector_type(4)));

// async global->LDS DMA, 16B per lane; LDS dest must be wave-uniform-base + lane*16
#define GLOAD_LDS16(g, l) __builtin_amdgcn_global_load_lds( \
    (const __attribute__((address_space(1))) void*)(g), \
    (__attribute__((address_space(3))) void*)(l), 16, 0, 0)

__device__ __forceinline__ short f2bf(float f) {
  union { float f; uint32_t u; } v; v.f = f;
  uint32_t r = (v.u + 0x7FFFu + ((v.u >> 16) & 1u)) >> 16;
  return (short)(uint16_t)r;
}

// ---------------- fp32 -> bf16 convert (vectorized x8) ----------------
__global__ void cvt_kernel(const float* __restrict__ src, short* __restrict__ dst, int n8) {
  int stride = gridDim.x * blockDim.x;
  for (int i = blockIdx.x * blockDim.x + threadIdx.x; i < n8; i += stride) {
    const float4* s4 = (const float4*)src + 2 * (size_t)i;
    float4 a = s4[0], b = s4[1];
    s16x8 o;
    o[0] = f2bf(a.x); o[1] = f2bf(a.y); o[2] = f2bf(a.z); o[3] = f2bf(a.w);
    o[4] = f2bf(b.x); o[5] = f2bf(b.y); o[6] = f2bf(b.z); o[7] = f2bf(b.w);
    *((s16x8*)dst + i) = o;
  }
}

// ---------------- weight transpose + convert: W[K][N] f32 -> Wt[N][K] bf16 ----------------
__global__ void twkernel(const float* __restrict__ W, short* __restrict__ Wt) {
  __shared__ __align__(16) short t[64][65];
  int lx = threadIdx.x & 63, ly = threadIdx.x >> 6;
  int c0 = (blockIdx.x & 15) * 64, r0 = (blockIdx.x >> 4) * 64;
  #pragma unroll
  for (int i = ly; i < 64; i += 4) t[i][lx] = f2bf(W[(size_t)(r0 + i) * DM + c0 + lx]);
  __syncthreads();
  #pragma unroll
  for (int i = ly; i < 64; i += 4) Wt[(size_t)(c0 + i) * DM + r0 + lx] = t[lx][i];
}

// ---------------- fused QKV projection GEMM ----------------
// A = Acat bf16 [18432][1024] (rows: 2048 q, 8192 k, 8192 v)
// Wt bf16 [N=1024][K=1024]; C = A * Wt^T. 128x128 tile, BK=32, 4 waves.
// Staging via global_load_lds width=16 (m97 structure, m193: +67% vs width-4 / reg-staged).
__global__ __launch_bounds__(256) void proj_gemm(
    const short* __restrict__ Acat,
    const short* __restrict__ Wqt, const short* __restrict__ Wkt, const short* __restrict__ Wvt,
    const float* __restrict__ bq, const float* __restrict__ bk, const float* __restrict__ bv,
    short* __restrict__ Qp, short* __restrict__ Kp, short* __restrict__ Vp)
{
  __shared__ __align__(16) short As[128 * 32];
  __shared__ __align__(16) short Bs[128 * 32];
  int tid = threadIdx.x, lane = tid & 63, wid = tid >> 6;
  int bm = blockIdx.x >> 3, bn = blockIdx.x & 7;
  int m0 = bm * 128, n0 = bn * 128;
  int seg = (m0 < MQ) ? 0 : (m0 < MQ + MK) ? 1 : 2;
  const short* Wt = (seg == 0) ? Wqt : (seg == 1) ? Wkt : Wvt;
  const float* bias = (seg == 0) ? bq : (seg == 1) ? bk : bv;

  int off = tid * 16;                    // byte offset within 8KB tile (= wave base + lane*16)
  int arow = off >> 6;                   // 0..63 (row this thread stages)
  int acol = (off & 63) >> 1;            // element col offset 0/8/16/24
  int wr = wid >> 1, wc = wid & 1;
  int l15 = lane & 15, lh8 = (lane >> 4) * 8;

  f32x4 acc[4][4] = {};

  const short* gA0 = Acat + (size_t)(m0 + arow) * DM + acol;
  const short* gA1 = Acat + (size_t)(m0 + arow + 64) * DM + acol;
  const short* gB0 = Wt + (size_t)(n0 + arow) * DM + acol;
  const short* gB1 = Wt + (size_t)(n0 + arow + 64) * DM + acol;

  for (int kt = 0; kt < 32; ++kt) {
    int k0 = kt * 32;
    __syncthreads();   // previous compute done reading As/Bs
    GLOAD_LDS16(gA0 + k0, (char*)As + off);
    GLOAD_LDS16(gA1 + k0, (char*)As + off + 4096);
    GLOAD_LDS16(gB0 + k0, (char*)Bs + off);
    GLOAD_LDS16(gB1 + k0, (char*)Bs + off + 4096);
    __syncthreads();   // compiler drains vmcnt(0) before s_barrier -> tile visible
    s16x8 af[4], bfr[4];
    #pragma unroll
    for (int mi = 0; mi < 4; ++mi)
      af[mi] = *(const s16x8*)((const char*)As + ((wr * 64 + mi * 16 + l15) * 32 + lh8) * 2);
    #pragma unroll
    for (int ni = 0; ni < 4; ++ni)
      bfr[ni] = *(const s16x8*)((const char*)Bs + ((wc * 64 + ni * 16 + l15) * 32 + lh8) * 2);
    #pragma unroll
    for (int mi = 0; mi < 4; ++mi)
      #pragma unroll
      for (int ni = 0; ni < 4; ++ni)
        acc[mi][ni] = __builtin_amdgcn_mfma_f32_16x16x32_bf16(af[mi], bfr[ni], acc[mi][ni], 0, 0, 0);
  }

  // epilogue: bias add + scatter to head-major layouts
  #pragma unroll
  for (int mi = 0; mi < 4; ++mi) {
    #pragma unroll
    for (int ni = 0; ni < 4; ++ni) {
      int col = n0 + wc * 64 + ni * 16 + l15;
      int h = col >> 6, d = col & 63;
      float bb = bias[col];
      #pragma unroll
      for (int r = 0; r < 4; ++r) {
        int row = m0 + wr * 64 + mi * 16 + (lane >> 4) * 4 + r;
        short v16 = f2bf(acc[mi][ni][r] + bb);
        if (seg == 0) {
          int b = row >> 10, sq = row & 1023;
          Qp[((size_t)(b * NH + h) * SQ + sq) * HD + d] = v16;
        } else if (seg == 1) {
          int kr = row - MQ; int b = kr >> 12, sk = kr & 4095;
          Kp[((size_t)(b * NH + h) * SK + sk) * HD + d] = v16;
        } else {
          int vr = row - (MQ + MK); int b = vr >> 12, sk = vr & 4095;
          Vp[((size_t)(b * NH + h) * HD + d) * SK + sk] = v16;
        }
      }
    }
  }
}

// ---------------- flash attention ----------------
// grid: 32 bh * 16 qtiles = 512 blocks; 4 waves x 16 q-rows = 64 rows/block.
__global__ __launch_bounds__(256) void attn_kernel(
    const short* __restrict__ Qp, const short* __restrict__ Kp, const short* __restrict__ Vp,
    const int* __restrict__ kmask, short* __restrict__ ctx)
{
  __shared__ __align__(16) short Ks[32 * 64];   // [sk][d]
  __shared__ __align__(16) short Vs[64 * 32];   // [d][sk]
  __shared__ __align__(16) short Ps[4][16 * 32];
  __shared__ float madd[SK];

  int tid = threadIdx.x, lane = tid & 63, wid = tid >> 6;
  int bh = blockIdx.x >> 4, qt = blockIdx.x & 15;
  int b = bh >> 4, h = bh & 15;
  const short* Qb = Qp + (size_t)bh * SQ * HD;
  const short* Kb = Kp + (size_t)bh * SK * HD;
  const short* Vb = Vp + (size_t)bh * HD * SK;
  const int* kmb = kmask + b * SK;

  for (int i = tid; i < SK; i += 256) madd[i] = kmb[i] ? 0.0f : -1e9f;

  int l15 = lane & 15, lh = lane >> 4, lh8 = lh * 8;
  int q0 = qt * 64 + wid * 16;

  s16x8 aq[2];
  aq[0] = *(const s16x8*)(Qb + (size_t)(q0 + l15) * HD + lh8);
  aq[1] = *(const s16x8*)(Qb + (size_t)(q0 + l15) * HD + 32 + lh8);

  f32x4 o[4] = {};
  float m_run[4], l_run[4];
  #pragma unroll
  for (int r = 0; r < 4; ++r) { m_run[r] = -3.0e38f; l_run[r] = 0.0f; }

  int krow = tid >> 3, kcol = (tid & 7) * 8;   // K tile [32][64]
  int vrow = tid >> 2, vcol = (tid & 3) * 8;   // V tile [64][32]
  s16x8 rk, rv;
#define ALOADS(t) { \
    rk = *(const s16x8*)(Kb + (size_t)((t) * 32 + krow) * HD + kcol); \
    rv = *(const s16x8*)(Vb + (size_t)vrow * SK + (t) * 32 + vcol); }

  ALOADS(0);
  const float scale = 0.125f;
  for (int t = 0; t < 128; ++t) {
    __syncthreads();                    // all waves done reading Ks/Vs (and madd at t=0)
    *(s16x8*)((char*)Ks + tid * 16) = rk;
    *(s16x8*)((char*)Vs + tid * 16) = rv;
    __syncthreads();                    // staged tile visible
    if (t < 127) ALOADS(t + 1);         // prefetch under compute

    // S = Q K^T  (16 q-rows x 32 sk-cols)
    f32x4 sc[2] = {};
    #pragma unroll
    for (int ni = 0; ni < 2; ++ni) {
      #pragma unroll
      for (int ks = 0; ks < 2; ++ks) {
        s16x8 kf = *(const s16x8*)((const char*)Ks + (((ni * 16 + l15) * 64) + ks * 32 + lh8) * 2);
        sc[ni] = __builtin_amdgcn_mfma_f32_16x16x32_bf16(aq[ks], kf, sc[ni], 0, 0, 0);
      }
    }
    // scale + additive mask
    #pragma unroll
    for (int ni = 0; ni < 2; ++ni) {
      float ma = madd[t * 32 + ni * 16 + l15];
      #pragma unroll
      for (int r = 0; r < 4; ++r) sc[ni][r] = sc[ni][r] * scale + ma;
    }
    // online softmax (rows live across 16 lanes of same lane>>4 group)
    float alpha[4];
    #pragma unroll
    for (int r = 0; r < 4; ++r) {
      float pm = fmaxf(sc[0][r], sc[1][r]);
      pm = fmaxf(pm, __shfl_xor(pm, 1));
      pm = fmaxf(pm, __shfl_xor(pm, 2));
      pm = fmaxf(pm, __shfl_xor(pm, 4));
      pm = fmaxf(pm, __shfl_xor(pm, 8));
      float mn = fmaxf(m_run[r], pm);
      alpha[r] = __expf(m_run[r] - mn);
      m_run[r] = mn;
      float p0 = __expf(sc[0][r] - mn);
      float p1 = __expf(sc[1][r] - mn);
      sc[0][r] = p0; sc[1][r] = p1;
      float rs = p0 + p1;
      rs += __shfl_xor(rs, 1);
      rs += __shfl_xor(rs, 2);
      rs += __shfl_xor(rs, 4);
      rs += __shfl_xor(rs, 8);
      l_run[r] = l_run[r] * alpha[r] + rs;
    }
    #pragma unroll
    for (int nd = 0; nd < 4; ++nd)
      #pragma unroll
      for (int r = 0; r < 4; ++r) o[nd][r] *= alpha[r];

    // P -> LDS (transpose C-layout to A-fragment layout)
    #pragma unroll
    for (int ni = 0; ni < 2; ++ni)
      #pragma unroll
      for (int r = 0; r < 4; ++r)
        Ps[wid][(lh * 4 + r) * 32 + ni * 16 + l15] = f2bf(sc[ni][r]);
    asm volatile("s_waitcnt lgkmcnt(0)" ::: "memory");

    s16x8 pa = *(const s16x8*)((const char*)&Ps[wid][0] + (l15 * 32 + lh8) * 2);
    #pragma unroll
    for (int nd = 0; nd < 4; ++nd) {
      s16x8 vf = *(const s16x8*)((const char*)Vs + ((nd * 16 + l15) * 32 + lh8) * 2);
      o[nd] = __builtin_amdgcn_mfma_f32_16x16x32_bf16(pa, vf, o[nd], 0, 0, 0);
    }
  }
#undef ALOADS

  #pragma unroll
  for (int nd = 0; nd < 4; ++nd) {
    #pragma unroll
    for (int r = 0; r < 4; ++r) {
      int q = q0 + lh * 4 + r;
      int d = nd * 16 + l15;
      float val = o[nd][r] / l_run[r];
      ctx[((size_t)(b * SQ + q)) * DM + h * HD + d] = f2bf(val);
    }
  }
}

// ---------------- output projection GEMM: out = ctx @ Wo + bo (fp32 out) ----------------
__global__ __launch_bounds__(256) void out_gemm(
    const short* __restrict__ Actx, const short* __restrict__ Wot,
    const float* __restrict__ bo, float* __restrict__ out)
{
  __shared__ __align__(16) short As[128 * 32];
  __shared__ __align__(16) short Bs[128 * 32];
  int tid = threadIdx.x, lane = tid & 63, wid = tid >> 6;
  int bm = blockIdx.x >> 3, bn = blockIdx.x & 7;
  int m0 = bm * 128, n0 = bn * 128;

  int off = tid * 16;
  int arow = off >> 6;
  int acol = (off & 63) >> 1;
  int wr = wid >> 1, wc = wid & 1;
  int l15 = lane & 15, lh8 = (lane >> 4) * 8;

  f32x4 acc[4][4] = {};

  const short* gA0 = Actx + (size_t)(m0 + arow) * DM + acol;
  const short* gA1 = Actx + (size_t)(m0 + arow + 64) * DM + acol;
  const short* gB0 = Wot + (size_t)(n0 + arow) * DM + acol;
  const short* gB1 = Wot + (size_t)(n0 + arow + 64) * DM + acol;

  for (int kt = 0; kt < 32; ++kt) {
    int k0 = kt * 32;
    __syncthreads();
    GLOAD_LDS16(gA0 + k0, (char*)As + off);
    GLOAD_LDS16(gA1 + k0, (char*)As + off + 4096);
    GLOAD_LDS16(gB0 + k0, (char*)Bs + off);
    GLOAD_LDS16(gB1 + k0, (char*)Bs + off + 4096);
    __syncthreads();
    s16x8 af[4], bfr[4];
    #pragma unroll
    for (int mi = 0; mi < 4; ++mi)
      af[mi] = *(const s16x8*)((const char*)As + ((wr * 64 + mi * 16 + l15) * 32 + lh8) * 2);
    #pragma unroll
    for (int ni = 0; ni < 4; ++ni)
      bfr[ni] = *(const s16x8*)((const char*)Bs + ((wc * 64 + ni * 16 + l15) * 32 + lh8) * 2);
    #pragma unroll
    for (int mi = 0; mi < 4; ++mi)
      #pragma unroll
      for (int ni = 0; ni < 4; ++ni)
        acc[mi][ni] = __builtin_amdgcn_mfma_f32_16x16x32_bf16(af[mi], bfr[ni], acc[mi][ni], 0, 0, 0);
  }

  #pragma unroll
  for (int mi = 0; mi < 4; ++mi) {
    #pragma unroll
    for (int ni = 0; ni < 4; ++ni) {
      int col = n0 + wc * 64 + ni * 16 + l15;
      float bb = bo[col];
      #pragma unroll
      for (int r = 0; r < 4; ++r) {
        int row = m0 + wr * 64 + mi * 16 + (lane >> 4) * 4 + r;
        out[(size_t)row * DM + col] = acc[mi][ni][r] + bb;
      }
    }
  }
}

extern "C" void kernel_launch(void* const* d_in, const int* in_sizes, int n_in,
                              void* d_out, int out_size, void* d_ws, size_t ws_size,
                              hipStream_t stream) {
  const float* query = (const float*)d_in[0];
  const float* key   = (const float*)d_in[1];
  const float* value = (const float*)d_in[2];
  const int*   kmask = (const int*)d_in[3];
  const float* Wq = (const float*)d_in[4];
  const float* bq = (const float*)d_in[5];
  const float* Wk = (const float*)d_in[6];
  const float* bk = (const float*)d_in[7];
  const float* Wv = (const float*)d_in[8];
  const float* bv = (const float*)d_in[9];
  const float* Wo = (const float*)d_in[10];
  const float* bo = (const float*)d_in[11];
  float* out = (float*)d_out;

  char* ws = (char*)d_ws;
  short* Acat = (short*)ws;                       // 18432*1024 bf16 = 36 MB
  short* Wqt  = (short*)(ws + (size_t)37748736);  // 4 x 1M bf16 = 8 MB
  short* Wkt  = Wqt + 1048576;
  short* Wvt  = Wkt + 1048576;
  short* Wot  = Wvt + 1048576;
  short* Qp   = Wot + 1048576;                    // [B,H,Sq,64]  4 MB
  short* Kp   = Qp + 2097152;                     // [B,H,Sk,64] 16 MB
  short* Vp   = Kp + 8388608;                     // [B,H,64,Sk] 16 MB
  short* ctx  = Vp + 8388608;                     // [B,Sq,1024]  4 MB

  short* qbf = Acat;
  short* kbf = Acat + 2097152;
  short* vbf = Acat + 2097152 + 8388608;

  cvt_kernel<<<1024, 256, 0, stream>>>(query, qbf, 2097152 / 8);
  cvt_kernel<<<2048, 256, 0, stream>>>(key,   kbf, 8388608 / 8);
  cvt_kernel<<<2048, 256, 0, stream>>>(value, vbf, 8388608 / 8);
  twkernel<<<256, 256, 0, stream>>>(Wq, Wqt);
  twkernel<<<256, 256, 0, stream>>>(Wk, Wkt);
  twkernel<<<256, 256, 0, stream>>>(Wv, Wvt);
  twkernel<<<256, 256, 0, stream>>>(Wo, Wot);
  proj_gemm<<<1152, 256, 0, stream>>>(Acat, Wqt, Wkt, Wvt, bq, bk, bv, Qp, Kp, Vp);
  attn_kernel<<<512, 256, 0, stream>>>(Qp, Kp, Vp, kmask, ctx);
  out_gemm<<<128, 256, 0, stream>>>(ctx, Wot, bo, out);
}

// Round 4
// 380.285 us; speedup vs baseline: 1.2731x; 1.2731x over previous
//
#include <hip/hip_runtime.h>
#include <stdint.h>

#define NH 16
#define HD 64
#define SQ 1024
#define SK 4096
#define DM 1024
#define MQ 2048      // B*Sq
#define MK 8192      // B*Sk
#define MTOT 18432   // MQ + MK + MK

typedef short s16x8 __attribute__((ext_vector_type(8)));
typedef float f32x4 __attribute__((ext_vector_type(4)));

// async global->LDS DMA, 16B per lane; LDS dest must be wave-uniform-base + lane*16
#define GLOAD_LDS16(g, l) __builtin_amdgcn_global_load_lds( \
    (const __attribute__((address_space(1))) void*)(g), \
    (__attribute__((address_space(3))) void*)(l), 16, 0, 0)

__device__ __forceinline__ short f2bf(float f) {   // RNE
  union { float f; uint32_t u; } v; v.f = f;
  uint32_t r = (v.u + 0x7FFFu + ((v.u >> 16) & 1u)) >> 16;
  return (short)(uint16_t)r;
}
__device__ __forceinline__ short f2bf_rz(float f) { // truncate (P values in [0,1])
  union { float f; uint32_t u; } v; v.f = f;
  return (short)(uint16_t)(v.u >> 16);
}

// ---------------- fp32 -> bf16 convert (vectorized x8) ----------------
__global__ void cvt_kernel(const float* __restrict__ src, short* __restrict__ dst, int n8) {
  int stride = gridDim.x * blockDim.x;
  for (int i = blockIdx.x * blockDim.x + threadIdx.x; i < n8; i += stride) {
    const float4* s4 = (const float4*)src + 2 * (size_t)i;
    float4 a = s4[0], b = s4[1];
    s16x8 o;
    o[0] = f2bf(a.x); o[1] = f2bf(a.y); o[2] = f2bf(a.z); o[3] = f2bf(a.w);
    o[4] = f2bf(b.x); o[5] = f2bf(b.y); o[6] = f2bf(b.z); o[7] = f2bf(b.w);
    *((s16x8*)dst + i) = o;
  }
}

// ---------------- weight transpose + convert: W[K][N] f32 -> Wt[N][K] bf16 ----------------
__global__ void twkernel(const float* __restrict__ W, short* __restrict__ Wt) {
  __shared__ __align__(16) short t[64][65];
  int lx = threadIdx.x & 63, ly = threadIdx.x >> 6;
  int c0 = (blockIdx.x & 15) * 64, r0 = (blockIdx.x >> 4) * 64;
  #pragma unroll
  for (int i = ly; i < 64; i += 4) t[i][lx] = f2bf(W[(size_t)(r0 + i) * DM + c0 + lx]);
  __syncthreads();
  #pragma unroll
  for (int i = ly; i < 64; i += 4) Wt[(size_t)(c0 + i) * DM + r0 + lx] = t[lx][i];
}

// ---------------- fused QKV projection GEMM ----------------
// A = Acat bf16 [18432][1024]; Wt bf16 [N][K]; C = A*Wt^T. 128x128 tile, BK=32.
// seg2 (V) epilogue transposes 16x16 subtiles via LDS so Vp is written [B,H,64,SK]
// with 32B-coalesced runs instead of 2B scatter at 8KB stride.
__global__ __launch_bounds__(256) void proj_gemm(
    const short* __restrict__ Acat,
    const short* __restrict__ Wqt, const short* __restrict__ Wkt, const short* __restrict__ Wvt,
    const float* __restrict__ bq, const float* __restrict__ bk, const float* __restrict__ bv,
    short* __restrict__ Qp, short* __restrict__ Kp, short* __restrict__ Vp)
{
  __shared__ __align__(16) short As[128 * 32];
  __shared__ __align__(16) short Bs[128 * 32];
  int tid = threadIdx.x, lane = tid & 63, wid = tid >> 6;
  int bm = blockIdx.x >> 3, bn = blockIdx.x & 7;
  int m0 = bm * 128, n0 = bn * 128;
  int seg = (m0 < MQ) ? 0 : (m0 < MQ + MK) ? 1 : 2;
  const short* Wt = (seg == 0) ? Wqt : (seg == 1) ? Wkt : Wvt;
  const float* bias = (seg == 0) ? bq : (seg == 1) ? bk : bv;

  int off = tid * 16;                    // byte offset within 8KB tile
  int arow = off >> 6;                   // 0..63
  int acol = (off & 63) >> 1;            // element col offset 0/8/16/24
  int wr = wid >> 1, wc = wid & 1;
  int l15 = lane & 15, g = lane >> 4, lh8 = g * 8;

  f32x4 acc[4][4] = {};

  const short* gA0 = Acat + (size_t)(m0 + arow) * DM + acol;
  const short* gA1 = Acat + (size_t)(m0 + arow + 64) * DM + acol;
  const short* gB0 = Wt + (size_t)(n0 + arow) * DM + acol;
  const short* gB1 = Wt + (size_t)(n0 + arow + 64) * DM + acol;

  for (int kt = 0; kt < 32; ++kt) {
    int k0 = kt * 32;
    __syncthreads();
    GLOAD_LDS16(gA0 + k0, (char*)As + off);
    GLOAD_LDS16(gA1 + k0, (char*)As + off + 4096);
    GLOAD_LDS16(gB0 + k0, (char*)Bs + off);
    GLOAD_LDS16(gB1 + k0, (char*)Bs + off + 4096);
    __syncthreads();
    s16x8 af[4], bfr[4];
    #pragma unroll
    for (int mi = 0; mi < 4; ++mi)
      af[mi] = *(const s16x8*)((const char*)As + ((wr * 64 + mi * 16 + l15) * 32 + lh8) * 2);
    #pragma unroll
    for (int ni = 0; ni < 4; ++ni)
      bfr[ni] = *(const s16x8*)((const char*)Bs + ((wc * 64 + ni * 16 + l15) * 32 + lh8) * 2);
    #pragma unroll
    for (int mi = 0; mi < 4; ++mi)
      #pragma unroll
      for (int ni = 0; ni < 4; ++ni)
        acc[mi][ni] = __builtin_amdgcn_mfma_f32_16x16x32_bf16(af[mi], bfr[ni], acc[mi][ni], 0, 0, 0);
  }

  __syncthreads();   // all waves done with As/Bs (epilogue reuses As as scratch)

  if (seg == 2) {
    // transpose each 16x16 subtile via wave-private LDS, store coalesced to Vp[B,H,64,SK]
    short* tw = (short*)As + wid * 288;   // [16][18] per wave
    int vbase = m0 - (MQ + MK) + wr * 64;
    #pragma unroll
    for (int mi = 0; mi < 4; ++mi) {
      int vr = vbase + mi * 16 + l15;     // sk index for the store phase (lane = l15)
      int bb2 = vr >> 12, sk = vr & 4095;
      #pragma unroll
      for (int ni = 0; ni < 4; ++ni) {
        int col = n0 + wc * 64 + ni * 16; // 16-aligned -> h uniform over the subtile
        int h = col >> 6, d0 = col & 63;
        float bb = bias[col + l15];
        #pragma unroll
        for (int r = 0; r < 4; ++r)
          tw[(g * 4 + r) * 18 + l15] = f2bf(acc[mi][ni][r] + bb);
        // wave-private LDS, same-wave W->R is ordered
        #pragma unroll
        for (int j = 0; j < 4; ++j) {
          int dl = g * 4 + j;
          Vp[((size_t)(bb2 * NH + h) * HD + d0 + dl) * SK + sk] = tw[l15 * 18 + dl];
        }
      }
    }
  } else {
    #pragma unroll
    for (int mi = 0; mi < 4; ++mi) {
      #pragma unroll
      for (int ni = 0; ni < 4; ++ni) {
        int col = n0 + wc * 64 + ni * 16 + l15;
        int h = col >> 6, d = col & 63;
        float bb = bias[col];
        #pragma unroll
        for (int r = 0; r < 4; ++r) {
          int row = m0 + wr * 64 + mi * 16 + g * 4 + r;
          short v16 = f2bf(acc[mi][ni][r] + bb);
          if (seg == 0) {
            int b = row >> 10, sq = row & 1023;
            Qp[((size_t)(b * NH + h) * SQ + sq) * HD + d] = v16;
          } else {
            int kr = row - MQ; int b = kr >> 12, sk = kr & 4095;
            Kp[((size_t)(b * NH + h) * SK + sk) * HD + d] = v16;
          }
        }
      }
    }
  }
}

// ---------------- flash attention ----------------
// grid 512: bh = bid&31 (same bh -> same XCD since bid%8==bh%8), qt = bid>>5.
// KVBLK=64, 4 waves x 16 q-rows. All LDS tiles XOR-swizzled: byte ^= ((row&7)<<4).
__global__ __launch_bounds__(256) void attn_kernel(
    const short* __restrict__ Qp, const short* __restrict__ Kp, const short* __restrict__ Vp,
    const int* __restrict__ kmask, short* __restrict__ ctx)
{
  __shared__ __align__(16) short Ks[64 * 64];    // [sk][d] swizzled
  __shared__ __align__(16) short Vs[64 * 64];    // [d][sk] swizzled
  __shared__ __align__(16) short Ps[4][16 * 64]; // per-wave [q][k] swizzled
  __shared__ float madd[SK];

  int tid = threadIdx.x, lane = tid & 63, wid = tid >> 6;
  int bh = blockIdx.x & 31, qt = blockIdx.x >> 5;
  int b = bh >> 4, h = bh & 15;
  const short* Qb = Qp + (size_t)bh * SQ * HD;
  const short* Kb = Kp + (size_t)bh * SK * HD;
  const short* Vb = Vp + (size_t)bh * HD * SK;
  const int* kmb = kmask + b * SK;

  for (int i = tid; i < SK; i += 256) madd[i] = kmb[i] ? 0.0f : -1e9f;

  int l15 = lane & 15, g = lane >> 4, lh8 = g * 8;
  int q0 = qt * 64 + wid * 16;
  int swz = (l15 & 7) << 4;

  s16x8 aq[2];
  aq[0] = *(const s16x8*)(Qb + (size_t)(q0 + l15) * HD + lh8);
  aq[1] = *(const s16x8*)(Qb + (size_t)(q0 + l15) * HD + 32 + lh8);

  f32x4 o[4] = {};
  float m_run[4], l_run[4];
  #pragma unroll
  for (int r = 0; r < 4; ++r) { m_run[r] = -3.0e38f; l_run[r] = 0.0f; }

  int srow = tid >> 3, scEl = (tid & 7) * 8;     // staging: row, elem-col
  int wsoff = srow * 128 + ((scEl * 2) ^ ((srow & 7) << 4));  // swizzled byte offset

  s16x8 rk0, rk1, rv0, rv1;
#define ALOADS(t) { \
    rk0 = *(const s16x8*)(Kb + (size_t)((t) * 64 + srow) * HD + scEl); \
    rk1 = *(const s16x8*)(Kb + (size_t)((t) * 64 + srow + 32) * HD + scEl); \
    rv0 = *(const s16x8*)(Vb + (size_t)srow * SK + (t) * 64 + scEl); \
    rv1 = *(const s16x8*)(Vb + (size_t)(srow + 32) * SK + (t) * 64 + scEl); }

  ALOADS(0);
  const float sscale = 0.18033688f;   // 0.125 * log2(e); softmax in exp2 domain
  for (int t = 0; t < 64; ++t) {
    __syncthreads();                  // waves done reading previous tile (and madd at t=0)
    *(s16x8*)((char*)Ks + wsoff) = rk0;
    *(s16x8*)((char*)Ks + wsoff + 4096) = rk1;
    *(s16x8*)((char*)Vs + wsoff) = rv0;
    *(s16x8*)((char*)Vs + wsoff + 4096) = rv1;
    __syncthreads();                  // staged tile visible
    if (t < 63) ALOADS(t + 1);        // prefetch under compute

    // S = Q K^T  (16 q-rows x 64 sk-cols)
    f32x4 sc[4] = {};
    #pragma unroll
    for (int ni = 0; ni < 4; ++ni) {
      #pragma unroll
      for (int ks = 0; ks < 2; ++ks) {
        s16x8 kf = *(const s16x8*)((const char*)Ks + (ni * 16 + l15) * 128 + ((ks * 64 + g * 16) ^ swz));
        sc[ni] = __builtin_amdgcn_mfma_f32_16x16x32_bf16(aq[ks], kf, sc[ni], 0, 0, 0);
      }
    }
    // scale (exp2 domain) + additive mask
    #pragma unroll
    for (int ni = 0; ni < 4; ++ni) {
      float ma = madd[t * 64 + ni * 16 + l15];
      #pragma unroll
      for (int r = 0; r < 4; ++r) sc[ni][r] = sc[ni][r] * sscale + ma;
    }
    // online softmax (row spread over 16 lanes)
    float alpha[4];
    #pragma unroll
    for (int r = 0; r < 4; ++r) {
      float pm = fmaxf(fmaxf(sc[0][r], sc[1][r]), fmaxf(sc[2][r], sc[3][r]));
      pm = fmaxf(pm, __shfl_xor(pm, 1));
      pm = fmaxf(pm, __shfl_xor(pm, 2));
      pm = fmaxf(pm, __shfl_xor(pm, 4));
      pm = fmaxf(pm, __shfl_xor(pm, 8));
      float mn = fmaxf(m_run[r], pm);
      alpha[r] = exp2f(m_run[r] - mn);
      m_run[r] = mn;
      float rs = 0.f;
      #pragma unroll
      for (int ni = 0; ni < 4; ++ni) { float p = exp2f(sc[ni][r] - mn); sc[ni][r] = p; rs += p; }
      rs += __shfl_xor(rs, 1);
      rs += __shfl_xor(rs, 2);
      rs += __shfl_xor(rs, 4);
      rs += __shfl_xor(rs, 8);
      l_run[r] = l_run[r] * alpha[r] + rs;
    }
    #pragma unroll
    for (int nd = 0; nd < 4; ++nd)
      #pragma unroll
      for (int r = 0; r < 4; ++r) o[nd][r] *= alpha[r];

    // P -> LDS (C-layout -> A-frag layout), swizzled; wave-private
    char* PsW = (char*)&Ps[wid][0];
    #pragma unroll
    for (int ni = 0; ni < 4; ++ni) {
      #pragma unroll
      for (int r = 0; r < 4; ++r) {
        int prow = g * 4 + r;
        *(short*)(PsW + prow * 128 + (((ni * 16 + l15) * 2) ^ ((prow & 7) << 4))) = f2bf_rz(sc[ni][r]);
      }
    }
    // PV
    #pragma unroll
    for (int ks2 = 0; ks2 < 2; ++ks2) {
      s16x8 pa = *(const s16x8*)(PsW + l15 * 128 + ((ks2 * 64 + g * 16) ^ swz));
      #pragma unroll
      for (int nd = 0; nd < 4; ++nd) {
        s16x8 vf = *(const s16x8*)((const char*)Vs + (nd * 16 + l15) * 128 + ((ks2 * 64 + g * 16) ^ swz));
        o[nd] = __builtin_amdgcn_mfma_f32_16x16x32_bf16(pa, vf, o[nd], 0, 0, 0);
      }
    }
  }
#undef ALOADS

  #pragma unroll
  for (int nd = 0; nd < 4; ++nd) {
    #pragma unroll
    for (int r = 0; r < 4; ++r) {
      int q = q0 + g * 4 + r;
      int d = nd * 16 + l15;
      float val = o[nd][r] / l_run[r];
      ctx[((size_t)(b * SQ + q)) * DM + h * HD + d] = f2bf(val);
    }
  }
}

// ---------------- output projection GEMM: out = ctx @ Wo + bo (fp32 out) ----------------
__global__ __launch_bounds__(256) void out_gemm(
    const short* __restrict__ Actx, const short* __restrict__ Wot,
    const float* __restrict__ bo, float* __restrict__ out)
{
  __shared__ __align__(16) short As[128 * 32];
  __shared__ __align__(16) short Bs[128 * 32];
  int tid = threadIdx.x, lane = tid & 63, wid = tid >> 6;
  int bm = blockIdx.x >> 3, bn = blockIdx.x & 7;
  int m0 = bm * 128, n0 = bn * 128;

  int off = tid * 16;
  int arow = off >> 6;
  int acol = (off & 63) >> 1;
  int wr = wid >> 1, wc = wid & 1;
  int l15 = lane & 15, lh8 = (lane >> 4) * 8;

  f32x4 acc[4][4] = {};

  const short* gA0 = Actx + (size_t)(m0 + arow) * DM + acol;
  const short* gA1 = Actx + (size_t)(m0 + arow + 64) * DM + acol;
  const short* gB0 = Wot + (size_t)(n0 + arow) * DM + acol;
  const short* gB1 = Wot + (size_t)(n0 + arow + 64) * DM + acol;

  for (int kt = 0; kt < 32; ++kt) {
    int k0 = kt * 32;
    __syncthreads();
    GLOAD_LDS16(gA0 + k0, (char*)As + off);
    GLOAD_LDS16(gA1 + k0, (char*)As + off + 4096);
    GLOAD_LDS16(gB0 + k0, (char*)Bs + off);
    GLOAD_LDS16(gB1 + k0, (char*)Bs + off + 4096);
    __syncthreads();
    s16x8 af[4], bfr[4];
    #pragma unroll
    for (int mi = 0; mi < 4; ++mi)
      af[mi] = *(const s16x8*)((const char*)As + ((wr * 64 + mi * 16 + l15) * 32 + lh8) * 2);
    #pragma unroll
    for (int ni = 0; ni < 4; ++ni)
      bfr[ni] = *(const s16x8*)((const char*)Bs + ((wc * 64 + ni * 16 + l15) * 32 + lh8) * 2);
    #pragma unroll
    for (int mi = 0; mi < 4; ++mi)
      #pragma unroll
      for (int ni = 0; ni < 4; ++ni)
        acc[mi][ni] = __builtin_amdgcn_mfma_f32_16x16x32_bf16(af[mi], bfr[ni], acc[mi][ni], 0, 0, 0);
  }

  #pragma unroll
  for (int mi = 0; mi < 4; ++mi) {
    #pragma unroll
    for (int ni = 0; ni < 4; ++ni) {
      int col = n0 + wc * 64 + ni * 16 + l15;
      float bb = bo[col];
      #pragma unroll
      for (int r = 0; r < 4; ++r) {
        int row = m0 + wr * 64 + mi * 16 + (lane >> 4) * 4 + r;
        out[(size_t)row * DM + col] = acc[mi][ni][r] + bb;
      }
    }
  }
}

extern "C" void kernel_launch(void* const* d_in, const int* in_sizes, int n_in,
                              void* d_out, int out_size, void* d_ws, size_t ws_size,
                              hipStream_t stream) {
  const float* query = (const float*)d_in[0];
  const float* key   = (const float*)d_in[1];
  const float* value = (const float*)d_in[2];
  const int*   kmask = (const int*)d_in[3];
  const float* Wq = (const float*)d_in[4];
  const float* bq = (const float*)d_in[5];
  const float* Wk = (const float*)d_in[6];
  const float* bk = (const float*)d_in[7];
  const float* Wv = (const float*)d_in[8];
  const float* bv = (const float*)d_in[9];
  const float* Wo = (const float*)d_in[10];
  const float* bo = (const float*)d_in[11];
  float* out = (float*)d_out;

  char* ws = (char*)d_ws;
  short* Acat = (short*)ws;                       // 18432*1024 bf16 = 36 MB
  short* Wqt  = (short*)(ws + (size_t)37748736);  // 4 x 1M bf16 = 8 MB
  short* Wkt  = Wqt + 1048576;
  short* Wvt  = Wkt + 1048576;
  short* Wot  = Wvt + 1048576;
  short* Qp   = Wot + 1048576;                    // [B,H,Sq,64]  4 MB
  short* Kp   = Qp + 2097152;                     // [B,H,Sk,64] 16 MB
  short* Vp   = Kp + 8388608;                     // [B,H,64,Sk] 16 MB
  short* ctx  = Vp + 8388608;                     // [B,Sq,1024]  4 MB

  short* qbf = Acat;
  short* kbf = Acat + 2097152;
  short* vbf = Acat + 2097152 + 8388608;

  cvt_kernel<<<1024, 256, 0, stream>>>(query, qbf, 2097152 / 8);
  cvt_kernel<<<2048, 256, 0, stream>>>(key,   kbf, 8388608 / 8);
  cvt_kernel<<<2048, 256, 0, stream>>>(value, vbf, 8388608 / 8);
  twkernel<<<256, 256, 0, stream>>>(Wq, Wqt);
  twkernel<<<256, 256, 0, stream>>>(Wk, Wkt);
  twkernel<<<256, 256, 0, stream>>>(Wv, Wvt);
  twkernel<<<256, 256, 0, stream>>>(Wo, Wot);
  proj_gemm<<<1152, 256, 0, stream>>>(Acat, Wqt, Wkt, Wvt, bq, bk, bv, Qp, Kp, Vp);
  attn_kernel<<<512, 256, 0, stream>>>(Qp, Kp, Vp, kmask, ctx);
  out_gemm<<<128, 256, 0, stream>>>(ctx, Wot, bo, out);
}

// Round 5
// 355.392 us; speedup vs baseline: 1.3623x; 1.0700x over previous
//
#include <hip/hip_runtime.h>
#include <stdint.h>

#define NH 16
#define HD 64
#define SQ 1024
#define SK 4096
#define DM 1024
#define MQ 2048      // B*Sq
#define MK 8192      // B*Sk
#define MTOT 18432   // MQ + MK + MK

typedef short s16x8 __attribute__((ext_vector_type(8)));
typedef float f32x4 __attribute__((ext_vector_type(4)));

// async global->LDS DMA, 16B per lane; LDS dest must be wave-uniform-base + lane*16
#define GLOAD_LDS16(g, l) __builtin_amdgcn_global_load_lds( \
    (const __attribute__((address_space(1))) void*)(g), \
    (__attribute__((address_space(3))) void*)(l), 16, 0, 0)

__device__ __forceinline__ short f2bf(float f) {   // RNE
  union { float f; uint32_t u; } v; v.f = f;
  uint32_t r = (v.u + 0x7FFFu + ((v.u >> 16) & 1u)) >> 16;
  return (short)(uint16_t)r;
}
__device__ __forceinline__ short f2bf_rz(float f) { // truncate (P values >= 0)
  union { float f; uint32_t u; } v; v.f = f;
  return (short)(uint16_t)(v.u >> 16);
}

// ---------------- fp32 -> bf16 convert (vectorized x8) ----------------
__global__ void cvt_kernel(const float* __restrict__ src, short* __restrict__ dst, int n8) {
  int stride = gridDim.x * blockDim.x;
  for (int i = blockIdx.x * blockDim.x + threadIdx.x; i < n8; i += stride) {
    const float4* s4 = (const float4*)src + 2 * (size_t)i;
    float4 a = s4[0], b = s4[1];
    s16x8 o;
    o[0] = f2bf(a.x); o[1] = f2bf(a.y); o[2] = f2bf(a.z); o[3] = f2bf(a.w);
    o[4] = f2bf(b.x); o[5] = f2bf(b.y); o[6] = f2bf(b.z); o[7] = f2bf(b.w);
    *((s16x8*)dst + i) = o;
  }
}

// ---------------- weight transpose + convert: W[K][N] f32 -> Wt[N][K] bf16 ----------------
__global__ void twkernel(const float* __restrict__ W, short* __restrict__ Wt) {
  __shared__ __align__(16) short t[64][65];
  int lx = threadIdx.x & 63, ly = threadIdx.x >> 6;
  int c0 = (blockIdx.x & 15) * 64, r0 = (blockIdx.x >> 4) * 64;
  #pragma unroll
  for (int i = ly; i < 64; i += 4) t[i][lx] = f2bf(W[(size_t)(r0 + i) * DM + c0 + lx]);
  __syncthreads();
  #pragma unroll
  for (int i = ly; i < 64; i += 4) Wt[(size_t)(c0 + i) * DM + r0 + lx] = t[lx][i];
}

// ---------------- fused QKV projection GEMM ----------------
__global__ __launch_bounds__(256) void proj_gemm(
    const short* __restrict__ Acat,
    const short* __restrict__ Wqt, const short* __restrict__ Wkt, const short* __restrict__ Wvt,
    const float* __restrict__ bq, const float* __restrict__ bk, const float* __restrict__ bv,
    short* __restrict__ Qp, short* __restrict__ Kp, short* __restrict__ Vp)
{
  __shared__ __align__(16) short As[128 * 32];
  __shared__ __align__(16) short Bs[128 * 32];
  int tid = threadIdx.x, lane = tid & 63, wid = tid >> 6;
  int bm = blockIdx.x >> 3, bn = blockIdx.x & 7;
  int m0 = bm * 128, n0 = bn * 128;
  int seg = (m0 < MQ) ? 0 : (m0 < MQ + MK) ? 1 : 2;
  const short* Wt = (seg == 0) ? Wqt : (seg == 1) ? Wkt : Wvt;
  const float* bias = (seg == 0) ? bq : (seg == 1) ? bk : bv;

  int off = tid * 16;
  int arow = off >> 6;
  int acol = (off & 63) >> 1;
  int wr = wid >> 1, wc = wid & 1;
  int l15 = lane & 15, g = lane >> 4, lh8 = g * 8;

  f32x4 acc[4][4] = {};

  const short* gA0 = Acat + (size_t)(m0 + arow) * DM + acol;
  const short* gA1 = Acat + (size_t)(m0 + arow + 64) * DM + acol;
  const short* gB0 = Wt + (size_t)(n0 + arow) * DM + acol;
  const short* gB1 = Wt + (size_t)(n0 + arow + 64) * DM + acol;

  for (int kt = 0; kt < 32; ++kt) {
    int k0 = kt * 32;
    __syncthreads();
    GLOAD_LDS16(gA0 + k0, (char*)As + off);
    GLOAD_LDS16(gA1 + k0, (char*)As + off + 4096);
    GLOAD_LDS16(gB0 + k0, (char*)Bs + off);
    GLOAD_LDS16(gB1 + k0, (char*)Bs + off + 4096);
    __syncthreads();
    s16x8 af[4], bfr[4];
    #pragma unroll
    for (int mi = 0; mi < 4; ++mi)
      af[mi] = *(const s16x8*)((const char*)As + ((wr * 64 + mi * 16 + l15) * 32 + lh8) * 2);
    #pragma unroll
    for (int ni = 0; ni < 4; ++ni)
      bfr[ni] = *(const s16x8*)((const char*)Bs + ((wc * 64 + ni * 16 + l15) * 32 + lh8) * 2);
    #pragma unroll
    for (int mi = 0; mi < 4; ++mi)
      #pragma unroll
      for (int ni = 0; ni < 4; ++ni)
        acc[mi][ni] = __builtin_amdgcn_mfma_f32_16x16x32_bf16(af[mi], bfr[ni], acc[mi][ni], 0, 0, 0);
  }

  __syncthreads();   // epilogue reuses As as scratch

  if (seg == 2) {
    short* tw = (short*)As + wid * 288;   // [16][18] per wave
    int vbase = m0 - (MQ + MK) + wr * 64;
    #pragma unroll
    for (int mi = 0; mi < 4; ++mi) {
      int vr = vbase + mi * 16 + l15;
      int bb2 = vr >> 12, sk = vr & 4095;
      #pragma unroll
      for (int ni = 0; ni < 4; ++ni) {
        int col = n0 + wc * 64 + ni * 16;
        int h = col >> 6, d0 = col & 63;
        float bb = bias[col + l15];
        #pragma unroll
        for (int r = 0; r < 4; ++r)
          tw[(g * 4 + r) * 18 + l15] = f2bf(acc[mi][ni][r] + bb);
        #pragma unroll
        for (int j = 0; j < 4; ++j) {
          int dl = g * 4 + j;
          Vp[((size_t)(bb2 * NH + h) * HD + d0 + dl) * SK + sk] = tw[l15 * 18 + dl];
        }
      }
    }
  } else {
    #pragma unroll
    for (int mi = 0; mi < 4; ++mi) {
      #pragma unroll
      for (int ni = 0; ni < 4; ++ni) {
        int col = n0 + wc * 64 + ni * 16 + l15;
        int h = col >> 6, d = col & 63;
        float bb = bias[col];
        #pragma unroll
        for (int r = 0; r < 4; ++r) {
          int row = m0 + wr * 64 + mi * 16 + g * 4 + r;
          short v16 = f2bf(acc[mi][ni][r] + bb);
          if (seg == 0) {
            int b = row >> 10, sq = row & 1023;
            Qp[((size_t)(b * NH + h) * SQ + sq) * HD + d] = v16;
          } else {
            int kr = row - MQ; int b = kr >> 12, sk = kr & 4095;
            Kp[((size_t)(b * NH + h) * SK + sk) * HD + d] = v16;
          }
        }
      }
    }
  }
}

// ---------------- flash attention ----------------
// grid 512: bh = bid&31 (XCD locality), qt = bid>>5. KVBLK=64, double-buffered LDS,
// one barrier/iter. l via MFMA against ones (no sum shuffles). Defer-max THR=8 (exp2 dom).
__global__ __launch_bounds__(256) void attn_kernel(
    const short* __restrict__ Qp, const short* __restrict__ Kp, const short* __restrict__ Vp,
    const int* __restrict__ kmask, short* __restrict__ ctx)
{
  __shared__ __align__(16) short Ks[2][64 * 64];   // [sk][d] swizzled, dbuf
  __shared__ __align__(16) short Vs[2][64 * 64];   // [d][sk] swizzled, dbuf
  __shared__ __align__(16) short Ps[4][16 * 64];   // per-wave [q][k] swizzled
  __shared__ float madd[SK];

  int tid = threadIdx.x, lane = tid & 63, wid = tid >> 6;
  int bh = blockIdx.x & 31, qt = blockIdx.x >> 5;
  int b = bh >> 4, h = bh & 15;
  const short* Qb = Qp + (size_t)bh * SQ * HD;
  const short* Kb = Kp + (size_t)bh * SK * HD;
  const short* Vb = Vp + (size_t)bh * HD * SK;
  const int* kmb = kmask + b * SK;

  for (int i = tid; i < SK; i += 256) madd[i] = kmb[i] ? 0.0f : -1e9f;

  int l15 = lane & 15, g = lane >> 4, lh8 = g * 8;
  int q0 = qt * 64 + wid * 16;
  int swz = (l15 & 7) << 4;

  s16x8 aq[2];
  aq[0] = *(const s16x8*)(Qb + (size_t)(q0 + l15) * HD + lh8);
  aq[1] = *(const s16x8*)(Qb + (size_t)(q0 + l15) * HD + 32 + lh8);

  s16x8 ones;
  #pragma unroll
  for (int j = 0; j < 8; ++j) ones[j] = (short)0x3F80;  // bf16 1.0

  f32x4 o[4] = {};
  f32x4 ol = {};                      // row-sum accumulator (l) via MFMA
  float m_run[4];
  #pragma unroll
  for (int r = 0; r < 4; ++r) m_run[r] = -3.0e38f;

  int srow = tid >> 3, scEl = (tid & 7) * 8;
  int wsoff = srow * 128 + ((scEl * 2) ^ ((srow & 7) << 4));  // swizzled byte offset

  s16x8 rk0, rk1, rv0, rv1;
#define ALOADS(t) { \
    rk0 = *(const s16x8*)(Kb + (size_t)((t) * 64 + srow) * HD + scEl); \
    rk1 = *(const s16x8*)(Kb + (size_t)((t) * 64 + srow + 32) * HD + scEl); \
    rv0 = *(const s16x8*)(Vb + (size_t)srow * SK + (t) * 64 + scEl); \
    rv1 = *(const s16x8*)(Vb + (size_t)(srow + 32) * SK + (t) * 64 + scEl); }
#define STAGE(bi) { \
    char* kb_ = (char*)Ks[bi]; char* vb_ = (char*)Vs[bi]; \
    *(s16x8*)(kb_ + wsoff) = rk0; *(s16x8*)(kb_ + wsoff + 4096) = rk1; \
    *(s16x8*)(vb_ + wsoff) = rv0; *(s16x8*)(vb_ + wsoff + 4096) = rv1; }

  ALOADS(0); STAGE(0); ALOADS(1);
  __syncthreads();                    // buf0 + madd visible

  const float sscale = 0.18033688f;   // 0.125 * log2(e); softmax in exp2 domain
  for (int t = 0; t < 64; ++t) {
    int cur = t & 1;
    if (t < 63) STAGE(cur ^ 1);       // stage tile t+1 (regs) into other buffer
    if (t < 62) ALOADS(t + 2);        // prefetch tile t+2 under compute
    const char* KsB = (const char*)Ks[cur];
    const char* VsB = (const char*)Vs[cur];

    // S = Q K^T  (16 q-rows x 64 sk-cols)
    f32x4 sc[4] = {};
    __builtin_amdgcn_s_setprio(1);
    #pragma unroll
    for (int ni = 0; ni < 4; ++ni) {
      #pragma unroll
      for (int ks = 0; ks < 2; ++ks) {
        s16x8 kf = *(const s16x8*)(KsB + (ni * 16 + l15) * 128 + ((ks * 64 + g * 16) ^ swz));
        sc[ni] = __builtin_amdgcn_mfma_f32_16x16x32_bf16(aq[ks], kf, sc[ni], 0, 0, 0);
      }
    }
    __builtin_amdgcn_s_setprio(0);

    // scale (exp2 domain) + additive mask
    #pragma unroll
    for (int ni = 0; ni < 4; ++ni) {
      float ma = madd[t * 64 + ni * 16 + l15];
      #pragma unroll
      for (int r = 0; r < 4; ++r) sc[ni][r] = sc[ni][r] * sscale + ma;
    }

    // row max (16 lanes per row) + defer-max decision
    float pm[4];
    int upd = 0;
    #pragma unroll
    for (int r = 0; r < 4; ++r) {
      float p = fmaxf(fmaxf(sc[0][r], sc[1][r]), fmaxf(sc[2][r], sc[3][r]));
      p = fmaxf(p, __shfl_xor(p, 1));
      p = fmaxf(p, __shfl_xor(p, 2));
      p = fmaxf(p, __shfl_xor(p, 4));
      p = fmaxf(p, __shfl_xor(p, 8));
      pm[r] = p;
      upd |= (p > m_run[r] + 8.0f);
    }
    if (__any(upd)) {                 // rare after warm-up; wave-uniform
      #pragma unroll
      for (int r = 0; r < 4; ++r) {
        float mn = fmaxf(m_run[r], pm[r]);
        float alpha = exp2f(m_run[r] - mn);
        m_run[r] = mn;
        #pragma unroll
        for (int nd = 0; nd < 4; ++nd) o[nd][r] *= alpha;
        ol[r] *= alpha;
      }
    }

    // P -> LDS (C-layout -> A-frag layout), swizzled; wave-private
    char* PsW = (char*)&Ps[wid][0];
    #pragma unroll
    for (int ni = 0; ni < 4; ++ni) {
      #pragma unroll
      for (int r = 0; r < 4; ++r) {
        float p = exp2f(sc[ni][r] - m_run[r]);
        int prow = g * 4 + r;
        *(short*)(PsW + prow * 128 + (((ni * 16 + l15) * 2) ^ ((prow & 7) << 4))) = f2bf_rz(p);
      }
    }
    asm volatile("s_waitcnt lgkmcnt(0)" ::: "memory");

    // PV + l accumulation (ones-matrix MFMA replaces sum shuffles)
    __builtin_amdgcn_s_setprio(1);
    #pragma unroll
    for (int ks2 = 0; ks2 < 2; ++ks2) {
      s16x8 pa = *(const s16x8*)(PsW + l15 * 128 + ((ks2 * 64 + g * 16) ^ swz));
      #pragma unroll
      for (int nd = 0; nd < 4; ++nd) {
        s16x8 vf = *(const s16x8*)(VsB + (nd * 16 + l15) * 128 + ((ks2 * 64 + g * 16) ^ swz));
        o[nd] = __builtin_amdgcn_mfma_f32_16x16x32_bf16(pa, vf, o[nd], 0, 0, 0);
      }
      ol = __builtin_amdgcn_mfma_f32_16x16x32_bf16(pa, ones, ol, 0, 0, 0);
    }
    __builtin_amdgcn_s_setprio(0);
    __syncthreads();                  // writes to buf[nxt] visible; reads of buf[cur] done
  }
#undef ALOADS
#undef STAGE

  #pragma unroll
  for (int nd = 0; nd < 4; ++nd) {
    #pragma unroll
    for (int r = 0; r < 4; ++r) {
      int q = q0 + g * 4 + r;
      int d = nd * 16 + l15;
      float val = o[nd][r] / ol[r];
      ctx[((size_t)(b * SQ + q)) * DM + h * HD + d] = f2bf(val);
    }
  }
}

// ---------------- output projection GEMM: out = ctx @ Wo + bo (fp32 out) ----------------
__global__ __launch_bounds__(256) void out_gemm(
    const short* __restrict__ Actx, const short* __restrict__ Wot,
    const float* __restrict__ bo, float* __restrict__ out)
{
  __shared__ __align__(16) short As[128 * 32];
  __shared__ __align__(16) short Bs[128 * 32];
  int tid = threadIdx.x, lane = tid & 63, wid = tid >> 6;
  int bm = blockIdx.x >> 3, bn = blockIdx.x & 7;
  int m0 = bm * 128, n0 = bn * 128;

  int off = tid * 16;
  int arow = off >> 6;
  int acol = (off & 63) >> 1;
  int wr = wid >> 1, wc = wid & 1;
  int l15 = lane & 15, lh8 = (lane >> 4) * 8;

  f32x4 acc[4][4] = {};

  const short* gA0 = Actx + (size_t)(m0 + arow) * DM + acol;
  const short* gA1 = Actx + (size_t)(m0 + arow + 64) * DM + acol;
  const short* gB0 = Wot + (size_t)(n0 + arow) * DM + acol;
  const short* gB1 = Wot + (size_t)(n0 + arow + 64) * DM + acol;

  for (int kt = 0; kt < 32; ++kt) {
    int k0 = kt * 32;
    __syncthreads();
    GLOAD_LDS16(gA0 + k0, (char*)As + off);
    GLOAD_LDS16(gA1 + k0, (char*)As + off + 4096);
    GLOAD_LDS16(gB0 + k0, (char*)Bs + off);
    GLOAD_LDS16(gB1 + k0, (char*)Bs + off + 4096);
    __syncthreads();
    s16x8 af[4], bfr[4];
    #pragma unroll
    for (int mi = 0; mi < 4; ++mi)
      af[mi] = *(const s16x8*)((const char*)As + ((wr * 64 + mi * 16 + l15) * 32 + lh8) * 2);
    #pragma unroll
    for (int ni = 0; ni < 4; ++ni)
      bfr[ni] = *(const s16x8*)((const char*)Bs + ((wc * 64 + ni * 16 + l15) * 32 + lh8) * 2);
    #pragma unroll
    for (int mi = 0; mi < 4; ++mi)
      #pragma unroll
      for (int ni = 0; ni < 4; ++ni)
        acc[mi][ni] = __builtin_amdgcn_mfma_f32_16x16x32_bf16(af[mi], bfr[ni], acc[mi][ni], 0, 0, 0);
  }

  #pragma unroll
  for (int mi = 0; mi < 4; ++mi) {
    #pragma unroll
    for (int ni = 0; ni < 4; ++ni) {
      int col = n0 + wc * 64 + ni * 16 + l15;
      float bb = bo[col];
      #pragma unroll
      for (int r = 0; r < 4; ++r) {
        int row = m0 + wr * 64 + mi * 16 + (lane >> 4) * 4 + r;
        out[(size_t)row * DM + col] = acc[mi][ni][r] + bb;
      }
    }
  }
}

extern "C" void kernel_launch(void* const* d_in, const int* in_sizes, int n_in,
                              void* d_out, int out_size, void* d_ws, size_t ws_size,
                              hipStream_t stream) {
  const float* query = (const float*)d_in[0];
  const float* key   = (const float*)d_in[1];
  const float* value = (const float*)d_in[2];
  const int*   kmask = (const int*)d_in[3];
  const float* Wq = (const float*)d_in[4];
  const float* bq = (const float*)d_in[5];
  const float* Wk = (const float*)d_in[6];
  const float* bk = (const float*)d_in[7];
  const float* Wv = (const float*)d_in[8];
  const float* bv = (const float*)d_in[9];
  const float* Wo = (const float*)d_in[10];
  const float* bo = (const float*)d_in[11];
  float* out = (float*)d_out;

  char* ws = (char*)d_ws;
  short* Acat = (short*)ws;                       // 18432*1024 bf16 = 36 MB
  short* Wqt  = (short*)(ws + (size_t)37748736);  // 4 x 1M bf16 = 8 MB
  short* Wkt  = Wqt + 1048576;
  short* Wvt  = Wkt + 1048576;
  short* Wot  = Wvt + 1048576;
  short* Qp   = Wot + 1048576;                    // [B,H,Sq,64]  4 MB
  short* Kp   = Qp + 2097152;                     // [B,H,Sk,64] 16 MB
  short* Vp   = Kp + 8388608;                     // [B,H,64,Sk] 16 MB
  short* ctx  = Vp + 8388608;                     // [B,Sq,1024]  4 MB

  short* qbf = Acat;
  short* kbf = Acat + 2097152;
  short* vbf = Acat + 2097152 + 8388608;

  cvt_kernel<<<1024, 256, 0, stream>>>(query, qbf, 2097152 / 8);
  cvt_kernel<<<2048, 256, 0, stream>>>(key,   kbf, 8388608 / 8);
  cvt_kernel<<<2048, 256, 0, stream>>>(value, vbf, 8388608 / 8);
  twkernel<<<256, 256, 0, stream>>>(Wq, Wqt);
  twkernel<<<256, 256, 0, stream>>>(Wk, Wkt);
  twkernel<<<256, 256, 0, stream>>>(Wv, Wvt);
  twkernel<<<256, 256, 0, stream>>>(Wo, Wot);
  proj_gemm<<<1152, 256, 0, stream>>>(Acat, Wqt, Wkt, Wvt, bq, bk, bv, Qp, Kp, Vp);
  attn_kernel<<<512, 256, 0, stream>>>(Qp, Kp, Vp, kmask, ctx);
  out_gemm<<<128, 256, 0, stream>>>(ctx, Wot, bo, out);
}

// Round 6
// 341.061 us; speedup vs baseline: 1.4195x; 1.0420x over previous
//
#include <hip/hip_runtime.h>
#include <stdint.h>

#define NH 16
#define HD 64
#define SQ 1024
#define SK 4096
#define DM 1024
#define MQ 2048      // B*Sq
#define MK 8192      // B*Sk
#define MTOT 18432   // MQ + MK + MK

typedef short s16x8 __attribute__((ext_vector_type(8)));
typedef float f32x4 __attribute__((ext_vector_type(4)));

// async global->LDS DMA, 16B per lane; LDS dest must be wave-uniform-base + lane*16
#define GLOAD_LDS16(g, l) __builtin_amdgcn_global_load_lds( \
    (const __attribute__((address_space(1))) void*)(g), \
    (__attribute__((address_space(3))) void*)(l), 16, 0, 0)

__device__ __forceinline__ short f2bf(float f) {   // RNE
  union { float f; uint32_t u; } v; v.f = f;
  uint32_t r = (v.u + 0x7FFFu + ((v.u >> 16) & 1u)) >> 16;
  return (short)(uint16_t)r;
}
__device__ __forceinline__ short f2bf_rz(float f) { // truncate (P values >= 0)
  union { float f; uint32_t u; } v; v.f = f;
  return (short)(uint16_t)(v.u >> 16);
}

// ---------------- fp32 -> bf16 convert (vectorized x8) ----------------
__global__ void cvt_kernel(const float* __restrict__ src, short* __restrict__ dst, int n8) {
  int stride = gridDim.x * blockDim.x;
  for (int i = blockIdx.x * blockDim.x + threadIdx.x; i < n8; i += stride) {
    const float4* s4 = (const float4*)src + 2 * (size_t)i;
    float4 a = s4[0], b = s4[1];
    s16x8 o;
    o[0] = f2bf(a.x); o[1] = f2bf(a.y); o[2] = f2bf(a.z); o[3] = f2bf(a.w);
    o[4] = f2bf(b.x); o[5] = f2bf(b.y); o[6] = f2bf(b.z); o[7] = f2bf(b.w);
    *((s16x8*)dst + i) = o;
  }
}

// ---------------- weight transpose + convert: W[K][N] f32 -> Wt[N][K] bf16 ----------------
__global__ void twkernel(const float* __restrict__ W, short* __restrict__ Wt) {
  __shared__ __align__(16) short t[64][65];
  int lx = threadIdx.x & 63, ly = threadIdx.x >> 6;
  int c0 = (blockIdx.x & 15) * 64, r0 = (blockIdx.x >> 4) * 64;
  #pragma unroll
  for (int i = ly; i < 64; i += 4) t[i][lx] = f2bf(W[(size_t)(r0 + i) * DM + c0 + lx]);
  __syncthreads();
  #pragma unroll
  for (int i = ly; i < 64; i += 4) Wt[(size_t)(c0 + i) * DM + r0 + lx] = t[lx][i];
}

// ---------------- fused QKV projection GEMM ----------------
// Epilogue: all segments store via per-wave LDS transpose staging -> 16B coalesced stores.
__global__ __launch_bounds__(256) void proj_gemm(
    const short* __restrict__ Acat,
    const short* __restrict__ Wqt, const short* __restrict__ Wkt, const short* __restrict__ Wvt,
    const float* __restrict__ bq, const float* __restrict__ bk, const float* __restrict__ bv,
    short* __restrict__ Qp, short* __restrict__ Kp, short* __restrict__ Vp)
{
  __shared__ __align__(16) short As[128 * 32];
  __shared__ __align__(16) short Bs[128 * 32];
  int tid = threadIdx.x, lane = tid & 63, wid = tid >> 6;
  int bm = blockIdx.x >> 3, bn = blockIdx.x & 7;
  int m0 = bm * 128, n0 = bn * 128;
  int seg = (m0 < MQ) ? 0 : (m0 < MQ + MK) ? 1 : 2;
  const short* Wt = (seg == 0) ? Wqt : (seg == 1) ? Wkt : Wvt;
  const float* bias = (seg == 0) ? bq : (seg == 1) ? bk : bv;

  int off = tid * 16;
  int arow = off >> 6;
  int acol = (off & 63) >> 1;
  int wr = wid >> 1, wc = wid & 1;
  int l15 = lane & 15, g = lane >> 4, lh8 = g * 8;

  f32x4 acc[4][4] = {};

  const short* gA0 = Acat + (size_t)(m0 + arow) * DM + acol;
  const short* gA1 = Acat + (size_t)(m0 + arow + 64) * DM + acol;
  const short* gB0 = Wt + (size_t)(n0 + arow) * DM + acol;
  const short* gB1 = Wt + (size_t)(n0 + arow + 64) * DM + acol;

  for (int kt = 0; kt < 32; ++kt) {
    int k0 = kt * 32;
    __syncthreads();
    GLOAD_LDS16(gA0 + k0, (char*)As + off);
    GLOAD_LDS16(gA1 + k0, (char*)As + off + 4096);
    GLOAD_LDS16(gB0 + k0, (char*)Bs + off);
    GLOAD_LDS16(gB1 + k0, (char*)Bs + off + 4096);
    __syncthreads();
    s16x8 af[4], bfr[4];
    #pragma unroll
    for (int mi = 0; mi < 4; ++mi)
      af[mi] = *(const s16x8*)((const char*)As + ((wr * 64 + mi * 16 + l15) * 32 + lh8) * 2);
    #pragma unroll
    for (int ni = 0; ni < 4; ++ni)
      bfr[ni] = *(const s16x8*)((const char*)Bs + ((wc * 64 + ni * 16 + l15) * 32 + lh8) * 2);
    #pragma unroll
    for (int mi = 0; mi < 4; ++mi)
      #pragma unroll
      for (int ni = 0; ni < 4; ++ni)
        acc[mi][ni] = __builtin_amdgcn_mfma_f32_16x16x32_bf16(af[mi], bfr[ni], acc[mi][ni], 0, 0, 0);
  }

  __syncthreads();   // epilogue reuses As as scratch

  if (seg == 2) {
    short* tw = (short*)As + wid * 288;   // [16][18] per wave
    int vbase = m0 - (MQ + MK) + wr * 64;
    #pragma unroll
    for (int mi = 0; mi < 4; ++mi) {
      int vr = vbase + mi * 16 + l15;
      int bb2 = vr >> 12, sk = vr & 4095;
      #pragma unroll
      for (int ni = 0; ni < 4; ++ni) {
        int col = n0 + wc * 64 + ni * 16;
        int h = col >> 6, d0 = col & 63;
        float bb = bias[col + l15];
        #pragma unroll
        for (int r = 0; r < 4; ++r)
          tw[(g * 4 + r) * 18 + l15] = f2bf(acc[mi][ni][r] + bb);
        #pragma unroll
        for (int j = 0; j < 4; ++j) {
          int dl = g * 4 + j;
          Vp[((size_t)(bb2 * NH + h) * HD + d0 + dl) * SK + sk] = tw[l15 * 18 + dl];
        }
      }
    }
  } else {
    // per-wave [16][64] shorts (2KB), XOR-swizzled; 16B coalesced global stores
    char* tw2 = (char*)As + wid * 2048;
    int hh = (n0 + wc * 64) >> 6;                  // head (constant per wave)
    short* outp = (seg == 0) ? Qp : Kp;
    int sdim = (seg == 0) ? SQ : SK;
    int rbase = (seg == 0) ? m0 : m0 - MQ;
    int rmask = (seg == 0) ? 1023 : 4095;
    int rshift = (seg == 0) ? 10 : 12;
    #pragma unroll
    for (int mi = 0; mi < 4; ++mi) {
      #pragma unroll
      for (int ni = 0; ni < 4; ++ni) {
        float bb = bias[n0 + wc * 64 + ni * 16 + l15];
        #pragma unroll
        for (int r = 0; r < 4; ++r) {
          int rw = g * 4 + r;
          *(short*)(tw2 + rw * 128 + (((ni * 16 + l15) * 2) ^ ((rw & 7) << 4))) =
              f2bf(acc[mi][ni][r] + bb);
        }
      }
      asm volatile("s_waitcnt lgkmcnt(0)" ::: "memory");
      #pragma unroll
      for (int pp = 0; pp < 2; ++pp) {
        int lr = pp * 8 + (lane >> 3);
        int ce = (lane & 7) * 8;                   // element offset within row (16B chunks)
        s16x8 v8 = *(const s16x8*)(tw2 + lr * 128 + ((ce * 2) ^ ((lr & 7) << 4)));
        int row = rbase + wr * 64 + mi * 16 + lr;
        int bI = row >> rshift, s = row & rmask;
        *(s16x8*)(outp + ((size_t)(bI * NH + hh) * sdim + s) * HD + ce) = v8;
      }
      asm volatile("s_waitcnt lgkmcnt(0)" ::: "memory");
    }
  }
}

// ---------------- flash attention ----------------
// Fixed-shift softmax (no row-max): p = exp2(S*scale*log2e + madd), madd = mask?-8:-1e9.
// Shift cancels in o/l; l via ones-MFMA. KVBLK=64, dbuf LDS, 1 barrier/iter.
__global__ __launch_bounds__(256) void attn_kernel(
    const short* __restrict__ Qp, const short* __restrict__ Kp, const short* __restrict__ Vp,
    const int* __restrict__ kmask, short* __restrict__ ctx)
{
  __shared__ __align__(16) short Ks[2][64 * 64];   // [sk][d] swizzled, dbuf
  __shared__ __align__(16) short Vs[2][64 * 64];   // [d][sk] swizzled, dbuf
  __shared__ __align__(16) short Ps[4][16 * 64];   // per-wave [q][k] swizzled
  __shared__ float madd[SK];

  int tid = threadIdx.x, lane = tid & 63, wid = tid >> 6;
  int bh = blockIdx.x & 31, qt = blockIdx.x >> 5;
  int b = bh >> 4, h = bh & 15;
  const short* Qb = Qp + (size_t)bh * SQ * HD;
  const short* Kb = Kp + (size_t)bh * SK * HD;
  const short* Vb = Vp + (size_t)bh * HD * SK;
  const int* kmb = kmask + b * SK;

  for (int i = tid; i < SK; i += 256) madd[i] = kmb[i] ? -8.0f : -1e9f;

  int l15 = lane & 15, g = lane >> 4, lh8 = g * 8;
  int q0 = qt * 64 + wid * 16;
  int swz = (l15 & 7) << 4;

  s16x8 aq[2];
  aq[0] = *(const s16x8*)(Qb + (size_t)(q0 + l15) * HD + lh8);
  aq[1] = *(const s16x8*)(Qb + (size_t)(q0 + l15) * HD + 32 + lh8);

  s16x8 ones;
  #pragma unroll
  for (int j = 0; j < 8; ++j) ones[j] = (short)0x3F80;  // bf16 1.0

  f32x4 o[4] = {};
  f32x4 ol = {};                      // row-sum accumulator (l) via ones-MFMA

  int srow = tid >> 3, scEl = (tid & 7) * 8;
  int wsoff = srow * 128 + ((scEl * 2) ^ ((srow & 7) << 4));  // swizzled byte offset

  s16x8 rk0, rk1, rv0, rv1;
#define ALOADS(t) { \
    rk0 = *(const s16x8*)(Kb + (size_t)((t) * 64 + srow) * HD + scEl); \
    rk1 = *(const s16x8*)(Kb + (size_t)((t) * 64 + srow + 32) * HD + scEl); \
    rv0 = *(const s16x8*)(Vb + (size_t)srow * SK + (t) * 64 + scEl); \
    rv1 = *(const s16x8*)(Vb + (size_t)(srow + 32) * SK + (t) * 64 + scEl); }
#define STAGE(bi) { \
    char* kb_ = (char*)Ks[bi]; char* vb_ = (char*)Vs[bi]; \
    *(s16x8*)(kb_ + wsoff) = rk0; *(s16x8*)(kb_ + wsoff + 4096) = rk1; \
    *(s16x8*)(vb_ + wsoff) = rv0; *(s16x8*)(vb_ + wsoff + 4096) = rv1; }

  ALOADS(0); STAGE(0); ALOADS(1);
  __syncthreads();                    // buf0 + madd visible

  const float sscale = 0.18033688f;   // 0.125 * log2(e); softmax in exp2 domain
  for (int t = 0; t < 64; ++t) {
    int cur = t & 1;
    if (t < 63) STAGE(cur ^ 1);       // stage tile t+1 (regs) into other buffer
    if (t < 62) ALOADS(t + 2);        // prefetch tile t+2 under compute
    const char* KsB = (const char*)Ks[cur];
    const char* VsB = (const char*)Vs[cur];

    // S = Q K^T  (16 q-rows x 64 sk-cols)
    f32x4 sc[4] = {};
    __builtin_amdgcn_s_setprio(1);
    #pragma unroll
    for (int ni = 0; ni < 4; ++ni) {
      #pragma unroll
      for (int ks = 0; ks < 2; ++ks) {
        s16x8 kf = *(const s16x8*)(KsB + (ni * 16 + l15) * 128 + ((ks * 64 + g * 16) ^ swz));
        sc[ni] = __builtin_amdgcn_mfma_f32_16x16x32_bf16(aq[ks], kf, sc[ni], 0, 0, 0);
      }
    }
    __builtin_amdgcn_s_setprio(0);

    // P = exp2(S*sscale + madd)  (fixed shift, no row-max) -> LDS (swizzled, wave-private)
    char* PsW = (char*)&Ps[wid][0];
    #pragma unroll
    for (int ni = 0; ni < 4; ++ni) {
      float ma = madd[t * 64 + ni * 16 + l15];
      #pragma unroll
      for (int r = 0; r < 4; ++r) {
        float p = exp2f(sc[ni][r] * sscale + ma);
        int prow = g * 4 + r;
        *(short*)(PsW + prow * 128 + (((ni * 16 + l15) * 2) ^ ((prow & 7) << 4))) = f2bf_rz(p);
      }
    }
    asm volatile("s_waitcnt lgkmcnt(0)" ::: "memory");

    // PV + l accumulation (ones-matrix MFMA)
    __builtin_amdgcn_s_setprio(1);
    #pragma unroll
    for (int ks2 = 0; ks2 < 2; ++ks2) {
      s16x8 pa = *(const s16x8*)(PsW + l15 * 128 + ((ks2 * 64 + g * 16) ^ swz));
      #pragma unroll
      for (int nd = 0; nd < 4; ++nd) {
        s16x8 vf = *(const s16x8*)(VsB + (nd * 16 + l15) * 128 + ((ks2 * 64 + g * 16) ^ swz));
        o[nd] = __builtin_amdgcn_mfma_f32_16x16x32_bf16(pa, vf, o[nd], 0, 0, 0);
      }
      ol = __builtin_amdgcn_mfma_f32_16x16x32_bf16(pa, ones, ol, 0, 0, 0);
    }
    __builtin_amdgcn_s_setprio(0);
    __syncthreads();                  // writes to buf[nxt] visible; reads of buf[cur] done
  }
#undef ALOADS
#undef STAGE

  #pragma unroll
  for (int nd = 0; nd < 4; ++nd) {
    #pragma unroll
    for (int r = 0; r < 4; ++r) {
      int q = q0 + g * 4 + r;
      int d = nd * 16 + l15;
      float val = o[nd][r] / ol[r];
      ctx[((size_t)(b * SQ + q)) * DM + h * HD + d] = f2bf(val);
    }
  }
}

// ---------------- output projection GEMM: out = ctx @ Wo + bo (fp32 out) ----------------
__global__ __launch_bounds__(256) void out_gemm(
    const short* __restrict__ Actx, const short* __restrict__ Wot,
    const float* __restrict__ bo, float* __restrict__ out)
{
  __shared__ __align__(16) short As[128 * 32];
  __shared__ __align__(16) short Bs[128 * 32];
  int tid = threadIdx.x, lane = tid & 63, wid = tid >> 6;
  int bm = blockIdx.x >> 3, bn = blockIdx.x & 7;
  int m0 = bm * 128, n0 = bn * 128;

  int off = tid * 16;
  int arow = off >> 6;
  int acol = (off & 63) >> 1;
  int wr = wid >> 1, wc = wid & 1;
  int l15 = lane & 15, lh8 = (lane >> 4) * 8;

  f32x4 acc[4][4] = {};

  const short* gA0 = Actx + (size_t)(m0 + arow) * DM + acol;
  const short* gA1 = Actx + (size_t)(m0 + arow + 64) * DM + acol;
  const short* gB0 = Wot + (size_t)(n0 + arow) * DM + acol;
  const short* gB1 = Wot + (size_t)(n0 + arow + 64) * DM + acol;

  for (int kt = 0; kt < 32; ++kt) {
    int k0 = kt * 32;
    __syncthreads();
    GLOAD_LDS16(gA0 + k0, (char*)As + off);
    GLOAD_LDS16(gA1 + k0, (char*)As + off + 4096);
    GLOAD_LDS16(gB0 + k0, (char*)Bs + off);
    GLOAD_LDS16(gB1 + k0, (char*)Bs + off + 4096);
    __syncthreads();
    s16x8 af[4], bfr[4];
    #pragma unroll
    for (int mi = 0; mi < 4; ++mi)
      af[mi] = *(const s16x8*)((const char*)As + ((wr * 64 + mi * 16 + l15) * 32 + lh8) * 2);
    #pragma unroll
    for (int ni = 0; ni < 4; ++ni)
      bfr[ni] = *(const s16x8*)((const char*)Bs + ((wc * 64 + ni * 16 + l15) * 32 + lh8) * 2);
    #pragma unroll
    for (int mi = 0; mi < 4; ++mi)
      #pragma unroll
      for (int ni = 0; ni < 4; ++ni)
        acc[mi][ni] = __builtin_amdgcn_mfma_f32_16x16x32_bf16(af[mi], bfr[ni], acc[mi][ni], 0, 0, 0);
  }

  #pragma unroll
  for (int mi = 0; mi < 4; ++mi) {
    #pragma unroll
    for (int ni = 0; ni < 4; ++ni) {
      int col = n0 + wc * 64 + ni * 16 + l15;
      float bb = bo[col];
      #pragma unroll
      for (int r = 0; r < 4; ++r) {
        int row = m0 + wr * 64 + mi * 16 + (lane >> 4) * 4 + r;
        out[(size_t)row * DM + col] = acc[mi][ni][r] + bb;
      }
    }
  }
}

extern "C" void kernel_launch(void* const* d_in, const int* in_sizes, int n_in,
                              void* d_out, int out_size, void* d_ws, size_t ws_size,
                              hipStream_t stream) {
  const float* query = (const float*)d_in[0];
  const float* key   = (const float*)d_in[1];
  const float* value = (const float*)d_in[2];
  const int*   kmask = (const int*)d_in[3];
  const float* Wq = (const float*)d_in[4];
  const float* bq = (const float*)d_in[5];
  const float* Wk = (const float*)d_in[6];
  const float* bk = (const float*)d_in[7];
  const float* Wv = (const float*)d_in[8];
  const float* bv = (const float*)d_in[9];
  const float* Wo = (const float*)d_in[10];
  const float* bo = (const float*)d_in[11];
  float* out = (float*)d_out;

  char* ws = (char*)d_ws;
  short* Acat = (short*)ws;                       // 18432*1024 bf16 = 36 MB
  short* Wqt  = (short*)(ws + (size_t)37748736);  // 4 x 1M bf16 = 8 MB
  short* Wkt  = Wqt + 1048576;
  short* Wvt  = Wkt + 1048576;
  short* Wot  = Wvt + 1048576;
  short* Qp   = Wot + 1048576;                    // [B,H,Sq,64]  4 MB
  short* Kp   = Qp + 2097152;                     // [B,H,Sk,64] 16 MB
  short* Vp   = Kp + 8388608;                     // [B,H,64,Sk] 16 MB
  short* ctx  = Vp + 8388608;                     // [B,Sq,1024]  4 MB

  short* qbf = Acat;
  short* kbf = Acat + 2097152;
  short* vbf = Acat + 2097152 + 8388608;

  cvt_kernel<<<1024, 256, 0, stream>>>(query, qbf, 2097152 / 8);
  cvt_kernel<<<2048, 256, 0, stream>>>(key,   kbf, 8388608 / 8);
  cvt_kernel<<<2048, 256, 0, stream>>>(value, vbf, 8388608 / 8);
  twkernel<<<256, 256, 0, stream>>>(Wq, Wqt);
  twkernel<<<256, 256, 0, stream>>>(Wk, Wkt);
  twkernel<<<256, 256, 0, stream>>>(Wv, Wvt);
  twkernel<<<256, 256, 0, stream>>>(Wo, Wot);
  proj_gemm<<<1152, 256, 0, stream>>>(Acat, Wqt, Wkt, Wvt, bq, bk, bv, Qp, Kp, Vp);
  attn_kernel<<<512, 256, 0, stream>>>(Qp, Kp, Vp, kmask, ctx);
  out_gemm<<<128, 256, 0, stream>>>(ctx, Wot, bo, out);
}